// Round 7
// baseline (213.015 us; speedup 1.0000x reference)
//
#include <hip/hip_runtime.h>
#include <hip/hip_bf16.h>
#include <math.h>

// Problem constants (from reference)
#define BATCH 4
#define SEQL 256          // L = C = 256
#define DMODEL 1024
#define DINNER 2048
#define DSTATE 16
#define OUTC 1024
#define NROWS (BATCH * SEQL)   // 1024
#define NCHUNK 4
#define CH 64             // SEQL / NCHUNK
#define XPZ 16            // x_proj split-K slices

typedef __attribute__((ext_vector_type(8))) short bf16x8;  // 8 bf16 = 4 VGPRs
typedef __attribute__((ext_vector_type(4))) float f32x4;   // MFMA C/D

// ---------------------------------------------------------------------------
// bf16 MFMA GEMM, C = A @ B^T, 64x64 tile, split-K over blockIdx.z.
// r6 (128x64, 2 blocks/CU) beat 128x128 (1/CU) by +10us -> continue the TLP
// axis: 64x64 gives 4 blocks/CU (16 waves/CU) on in_proj/out_proj.
// 4-deep LDS pipeline (32 KB), counted vmcnt (2 loads/stage/wave: 4/2/0),
// raw s_barrier. Wave layout: 2x2 waves, each owns 32x32 (acc[2][2]).
// K-sum order per output element identical to r6 -> bit-identical results.
// ---------------------------------------------------------------------------
__global__ __launch_bounds__(256) void gemm_t64(const __hip_bfloat16* __restrict__ A,
                                                const __hip_bfloat16* __restrict__ B,
                                                float* __restrict__ C,
                                                int M, int N, int K,
                                                int lda, int ldb) {
    __shared__ __hip_bfloat16 As[4][64 * 32];    // 16 KB
    __shared__ __hip_bfloat16 Bs[4][64 * 32];    // 16 KB
    const int t  = threadIdx.x;
    const int w  = t >> 6;          // wave 0..3
    const int ln = t & 63;
    const int wm = w >> 1, wn = w & 1;
    const int q  = ln >> 4, lr = ln & 15;
    const int m0 = blockIdx.y * 64;
    const int n0 = blockIdx.x * 64;
    const int Kpart = K / gridDim.z;
    const int kbase = blockIdx.z * Kpart;

    f32x4 acc[2][2] = {};

    const __hip_bfloat16* Ag = A + (size_t)m0 * lda + kbase;
    const __hip_bfloat16* Bg = B + (size_t)n0 * ldb + kbase;

    auto stage = [&](int k0, int buf) {
        const int c = w * 64 + ln;              // 0..255 -> row c>>2, col (c&3)*8
        const int r = c >> 2, col = (c & 3) * 8;
        __builtin_amdgcn_global_load_lds(
            (const __attribute__((address_space(1))) void*)(Ag + (size_t)r * lda + k0 + col),
            (__attribute__((address_space(3))) void*)(As[buf] + w * 512),
            16, 0, 0);
        __builtin_amdgcn_global_load_lds(
            (const __attribute__((address_space(1))) void*)(Bg + (size_t)r * ldb + k0 + col),
            (__attribute__((address_space(3))) void*)(Bs[buf] + w * 512),
            16, 0, 0);
    };

    const int nk = Kpart / 32;
    for (int s = 0; s < 3 && s < nk; ++s) stage(s * 32, s);

    for (int kk = 0; kk < nk; ++kk) {
        const int last = (kk + 2 < nk - 1) ? (kk + 2) : (nk - 1);
        const int nf = last - kk;      // younger stages in flight (2 loads each)
        if (nf >= 2)      asm volatile("s_waitcnt vmcnt(4)" ::: "memory");
        else if (nf == 1) asm volatile("s_waitcnt vmcnt(2)" ::: "memory");
        else              asm volatile("s_waitcnt vmcnt(0)" ::: "memory");
        __builtin_amdgcn_s_barrier();
        if (kk + 3 < nk) stage((kk + 3) * 32, (kk + 3) & 3);

        const int buf = kk & 3;
        bf16x8 af[2], bfr[2];
        #pragma unroll
        for (int i = 0; i < 2; ++i)
            af[i] = *(const bf16x8*)(As[buf] + (wm * 32 + i * 16 + lr) * 32 + q * 8);
        #pragma unroll
        for (int j = 0; j < 2; ++j)
            bfr[j] = *(const bf16x8*)(Bs[buf] + (wn * 32 + j * 16 + lr) * 32 + q * 8);
        #pragma unroll
        for (int i = 0; i < 2; ++i)
            #pragma unroll
            for (int j = 0; j < 2; ++j)
                acc[i][j] = __builtin_amdgcn_mfma_f32_16x16x32_bf16(af[i], bfr[j], acc[i][j], 0, 0, 0);
    }
    float* Cz = C + (size_t)blockIdx.z * M * N;
    #pragma unroll
    for (int i = 0; i < 2; ++i) {
        const int mrow = m0 + wm * 32 + i * 16 + q * 4;
        #pragma unroll
        for (int j = 0; j < 2; ++j) {
            const int ncol = n0 + wn * 32 + j * 16 + lr;
            #pragma unroll
            for (int r = 0; r < 4; ++r)
                Cz[(size_t)(mrow + r) * N + ncol] = acc[i][j][r];
        }
    }
}

// ---------------------------------------------------------------------------
// dt_proj as MFMA GEMM with fused bias + softplus epilogue. (K=64, 2 iters)
// ---------------------------------------------------------------------------
__global__ __launch_bounds__(256) void gemm_dtsp(const __hip_bfloat16* __restrict__ A,
                                                 const __hip_bfloat16* __restrict__ B,
                                                 const float* __restrict__ bd,
                                                 float* __restrict__ delta) {
    __shared__ __hip_bfloat16 As[2][128 * 32];
    __shared__ __hip_bfloat16 Bs[2][128 * 32];
    const int t  = threadIdx.x;
    const int w  = t >> 6;
    const int ln = t & 63;
    const int wm = w >> 1, wn = w & 1;
    const int q  = ln >> 4, lr = ln & 15;
    const int m0 = blockIdx.y * 128;
    const int n0 = blockIdx.x * 128;
    const int lda = 128, ldb = 64, N = 2048;

    f32x4 acc[4][4] = {};
    const __hip_bfloat16* Ag = A + (size_t)m0 * lda;
    const __hip_bfloat16* Bg = B + (size_t)n0 * ldb;

    auto stage = [&](int k0, int buf) {
        #pragma unroll
        for (int i = 0; i < 2; ++i) {
            const int c = (i * 4 + w) * 64 + ln;
            const int r = c >> 2, col = (c & 3) * 8;
            __builtin_amdgcn_global_load_lds(
                (const __attribute__((address_space(1))) void*)(Ag + (size_t)r * lda + k0 + col),
                (__attribute__((address_space(3))) void*)(As[buf] + (i * 4 + w) * 64 * 8),
                16, 0, 0);
            __builtin_amdgcn_global_load_lds(
                (const __attribute__((address_space(1))) void*)(Bg + (size_t)r * ldb + k0 + col),
                (__attribute__((address_space(3))) void*)(Bs[buf] + (i * 4 + w) * 64 * 8),
                16, 0, 0);
        }
    };

    stage(0, 0);
    stage(32, 1);
    #pragma unroll
    for (int kk = 0; kk < 2; ++kk) {
        if (kk == 0) asm volatile("s_waitcnt vmcnt(4)" ::: "memory");
        else         asm volatile("s_waitcnt vmcnt(0)" ::: "memory");
        __builtin_amdgcn_s_barrier();
        bf16x8 af[4], bfr[4];
        #pragma unroll
        for (int i = 0; i < 4; ++i)
            af[i] = *(const bf16x8*)(As[kk] + (wm * 64 + i * 16 + lr) * 32 + q * 8);
        #pragma unroll
        for (int j = 0; j < 4; ++j)
            bfr[j] = *(const bf16x8*)(Bs[kk] + (wn * 64 + j * 16 + lr) * 32 + q * 8);
        #pragma unroll
        for (int i = 0; i < 4; ++i)
            #pragma unroll
            for (int j = 0; j < 4; ++j)
                acc[i][j] = __builtin_amdgcn_mfma_f32_16x16x32_bf16(af[i], bfr[j], acc[i][j], 0, 0, 0);
    }
    #pragma unroll
    for (int i = 0; i < 4; ++i) {
        const int mrow = m0 + wm * 64 + i * 16 + q * 4;
        #pragma unroll
        for (int j = 0; j < 4; ++j) {
            const int ncol = n0 + wn * 64 + j * 16 + lr;
            const float bias = bd[ncol];
            #pragma unroll
            for (int r = 0; r < 4; ++r) {
                float v = acc[i][j][r] + bias;
                float sp = (v > 20.f) ? v : log1pf(__expf(v));
                delta[(size_t)(mrow + r) * N + ncol] = sp;
            }
        }
    }
}

// ---------------------------------------------------------------------------
// Reduce XPZ split-K partials of x_proj -> xdbl fp32 (1024x128) + xdblb bf16.
// ---------------------------------------------------------------------------
__global__ void xdbl_reduce_kernel(const float* __restrict__ part,
                                   float* __restrict__ xdbl,
                                   __hip_bfloat16* __restrict__ xdblb) {
    const int i = blockIdx.x * 256 + threadIdx.x;   // 1024*128
    float s = 0.f;
    #pragma unroll
    for (int z = 0; z < XPZ; ++z) s += part[(size_t)z * (1024 * 128) + i];
    xdbl[i] = s;
    xdblb[i] = __float2bfloat16(s);
}

// ---------------------------------------------------------------------------
// Fused fp32 -> bf16 casts, float4-vectorized (all regions are %4 sized).
// ---------------------------------------------------------------------------
#define R0 (1024 * 1024)
#define R1 (R0 + 4096 * 1024)
#define R2 (R1 + 2048 * 1024)
#define R3 (R2 + 128 * 2048)
#define R4 (R3 + 2048 * 64)

__device__ __forceinline__ ushort4 cvt4(float4 v) {
    __hip_bfloat16 h0 = __float2bfloat16(v.x);
    __hip_bfloat16 h1 = __float2bfloat16(v.y);
    __hip_bfloat16 h2 = __float2bfloat16(v.z);
    __hip_bfloat16 h3 = __float2bfloat16(v.w);
    ushort4 o;
    o.x = *reinterpret_cast<unsigned short*>(&h0);
    o.y = *reinterpret_cast<unsigned short*>(&h1);
    o.z = *reinterpret_cast<unsigned short*>(&h2);
    o.w = *reinterpret_cast<unsigned short*>(&h3);
    return o;
}

__global__ void cast_all_kernel(const float* __restrict__ x1,
                                const float* __restrict__ w_in,
                                const float* __restrict__ w_out,
                                const float* __restrict__ w_xp,
                                const float* __restrict__ w_dt,
                                __hip_bfloat16* __restrict__ xa,
                                __hip_bfloat16* __restrict__ wb1,
                                __hip_bfloat16* __restrict__ wob,
                                __hip_bfloat16* __restrict__ wpb,
                                __hip_bfloat16* __restrict__ wdb) {
    const int i = (blockIdx.x * 256 + threadIdx.x) * 4;
    if (i >= R4) return;
    if (i < R0) {
        *reinterpret_cast<ushort4*>(xa + i) = cvt4(*(const float4*)(x1 + i));
    } else if (i < R1) {
        int j = i - R0;
        *reinterpret_cast<ushort4*>(wb1 + j) = cvt4(*(const float4*)(w_in + j));
    } else if (i < R2) {
        int j = i - R1;
        *reinterpret_cast<ushort4*>(wob + j) = cvt4(*(const float4*)(w_out + j));
    } else if (i < R3) {
        int j = i - R2; int e = j >> 11;
        float4 v = (e < 96) ? *(const float4*)(w_xp + j) : float4{0.f, 0.f, 0.f, 0.f};
        *reinterpret_cast<ushort4*>(wpb + j) = cvt4(v);
    } else {
        int j = i - R3;
        *reinterpret_cast<ushort4*>(wdb + j) = cvt4(*(const float4*)(w_dt + j));
    }
}

// ---------------------------------------------------------------------------
// Depthwise causal conv1d (k=4, left pad 3) + bias + SiLU. Fully coalesced.
// ---------------------------------------------------------------------------
__global__ void conv_silu_kernel(const float* __restrict__ xz,
                                 const float* __restrict__ conv_w,
                                 const float* __restrict__ conv_b,
                                 float* __restrict__ xs,
                                 __hip_bfloat16* __restrict__ xsb) {
    int idx = blockIdx.x * blockDim.x + threadIdx.x;  // (b*L + l)*DINNER + d
    int d = idx & (DINNER - 1);
    int l = (idx >> 11) & (SEQL - 1);
    int b = idx >> 19;
    const float w0 = conv_w[d * 4 + 0];
    const float w1 = conv_w[d * 4 + 1];
    const float w2 = conv_w[d * 4 + 2];
    const float w3 = conv_w[d * 4 + 3];
    float acc = conv_b[d];
    const size_t base = (size_t)(b * SEQL) * (2 * DINNER) + d;
    if (l >= 3) acc += w0 * xz[base + (size_t)(l - 3) * (2 * DINNER)];
    if (l >= 2) acc += w1 * xz[base + (size_t)(l - 2) * (2 * DINNER)];
    if (l >= 1) acc += w2 * xz[base + (size_t)(l - 1) * (2 * DINNER)];
    acc += w3 * xz[base + (size_t)l * (2 * DINNER)];
    float v = acc / (1.f + __expf(-acc));
    xs[idx] = v;
    xsb[idx] = __float2bfloat16(v);
}

// ---------------------------------------------------------------------------
// 16-lane row sum via DPP row_ror rotations (no DS ops).
// ---------------------------------------------------------------------------
__device__ __forceinline__ float row_reduce16(float x) {
    x += __int_as_float(__builtin_amdgcn_update_dpp(0, __float_as_int(x), 0x128, 0xF, 0xF, true));
    x += __int_as_float(__builtin_amdgcn_update_dpp(0, __float_as_int(x), 0x124, 0xF, 0xF, true));
    x += __int_as_float(__builtin_amdgcn_update_dpp(0, __float_as_int(x), 0x122, 0xF, 0xF, true));
    x += __int_as_float(__builtin_amdgcn_update_dpp(0, __float_as_int(x), 0x121, 0xF, 0xF, true));
    return x;
}

// ---------------------------------------------------------------------------
// Chunk-parallel scan, phase A: per-chunk local recurrence (reads xs).
// Grid (128, B, 3): chunk 3's carry is never consumed -> not computed.
// ---------------------------------------------------------------------------
__global__ __launch_bounds__(256) void scan_carry_kernel(const float* __restrict__ delta,
                                                         const float* __restrict__ xs,
                                                         const float* __restrict__ xdbl,
                                                         const float* __restrict__ A_log,
                                                         float* __restrict__ carryL,
                                                         float* __restrict__ carryP) {
    __shared__ float sDU[CH][16][2];   // [l][dl][{dv, dv*xv}]
    __shared__ float sB[CH][16];       // [l][n]
    const int b = blockIdx.y, c = blockIdx.z, dg = blockIdx.x;
    const int t = threadIdx.x;
    const int dl = t >> 4, n = t & 15;
    const int d = dg * 16 + dl;
    const float a = -__expf(A_log[d * DSTATE + n]);
    const int srow = t >> 4, scol = t & 15;
    const int sd = dg * 16 + scol;
    const int rowbase = b * SEQL + c * CH;
    #pragma unroll
    for (int i = 0; i < 4; ++i) {
        const int row = rowbase + i * 16 + srow;
        const float dv = delta[(size_t)row * DINNER + sd];
        const float xv = xs[(size_t)row * DINNER + sd];
        sDU[i * 16 + srow][scol][0] = dv;
        sDU[i * 16 + srow][scol][1] = dv * xv;
        sB[i * 16 + srow][scol] = xdbl[row * 128 + 64 + scol];
    }
    __syncthreads();
    float h = 0.f, P = 1.f;
    #pragma unroll 16
    for (int l = 0; l < CH; ++l) {
        const float e = __expf(sDU[l][dl][0] * a);
        h = e * h + sDU[l][dl][1] * sB[l][n];
        P *= e;
    }
    const size_t ci = (((size_t)(b * NCHUNK + c)) * DINNER + d) * DSTATE + n;
    carryL[ci] = h;
    carryP[ci] = P;
}

// ---------------------------------------------------------------------------
// Chunk-parallel scan, phase B: combine carries (h = P_j h + L_j, j < c) then
// run the 64-step scan with y output (+D*xs, *silu(res), bf16).
// ---------------------------------------------------------------------------
__global__ __launch_bounds__(256) void scan_apply_kernel(const float* __restrict__ delta,
                                                         const float* __restrict__ xs,
                                                         const float* __restrict__ xdbl,
                                                         const float* __restrict__ xz,
                                                         const float* __restrict__ A_log,
                                                         const float* __restrict__ Dp,
                                                         const float* __restrict__ carryL,
                                                         const float* __restrict__ carryP,
                                                         __hip_bfloat16* __restrict__ ybb) {
    __shared__ float sDU[CH][16][2];   // [l][dl][{dv, dv*xv}]
    __shared__ float sBC[CH][16][2];   // [l][n][{B, C}]
    __shared__ float sGW[CH][16][2];   // [l][dl][{g, D*xv*g}]
    const int b = blockIdx.y, c = blockIdx.z, dg = blockIdx.x;
    const int t = threadIdx.x;
    const int dl = t >> 4, n = t & 15;
    const int d = dg * 16 + dl;
    const float a = -__expf(A_log[d * DSTATE + n]);
    const int srow = t >> 4, scol = t & 15;
    const int sd = dg * 16 + scol;
    const float Dstage = Dp[sd];
    const int rowbase = b * SEQL + c * CH;
    #pragma unroll
    for (int i = 0; i < 4; ++i) {
        const int row = rowbase + i * 16 + srow;
        const float dv = delta[(size_t)row * DINNER + sd];
        const float xv = xs[(size_t)row * DINNER + sd];
        const float r  = xz[(size_t)row * (2 * DINNER) + DINNER + sd];
        const float g = r / (1.f + __expf(-r));
        const int lr_ = i * 16 + srow;
        sDU[lr_][scol][0] = dv;
        sDU[lr_][scol][1] = dv * xv;
        sGW[lr_][scol][0] = g;
        sGW[lr_][scol][1] = Dstage * xv * g;
        sBC[lr_][scol][0] = xdbl[row * 128 + 64 + scol];
        sBC[lr_][scol][1] = xdbl[row * 128 + 80 + scol];
    }
    __syncthreads();
    float h = 0.f;
    for (int j = 0; j < c; ++j) {
        const size_t ci = (((size_t)(b * NCHUNK + j)) * DINNER + d) * DSTATE + n;
        h = carryP[ci] * h + carryL[ci];
    }
    #pragma unroll 16
    for (int l = 0; l < CH; ++l) {
        const float e = __expf(sDU[l][dl][0] * a);
        h = e * h + sDU[l][dl][1] * sBC[l][n][0];
        float pr = row_reduce16(h * sBC[l][n][1]);
        if (n == 0) {
            const float y = pr * sGW[l][dl][0] + sGW[l][dl][1];
            ybb[(size_t)(rowbase + l) * DINNER + d] = __float2bfloat16(y);
        }
    }
}

// ---------------------------------------------------------------------------
// LayerNorm over last dim (1024), fused 4-way split-K reduce of out_proj
// partials. block per row, 256 threads x 4 elems.
// ---------------------------------------------------------------------------
__global__ __launch_bounds__(256) void ln_kernel(const float* __restrict__ opart,
                                                 const float* __restrict__ lw,
                                                 const float* __restrict__ lb,
                                                 float* __restrict__ out) {
    __shared__ float red[8];
    const int row = blockIdx.x;
    const int t = threadIdx.x;
    float v[4];
    float s = 0.f, s2 = 0.f;
    #pragma unroll
    for (int i = 0; i < 4; ++i) {
        const int c = t + 256 * i;
        float acc = 0.f;
        #pragma unroll
        for (int z = 0; z < 4; ++z)
            acc += opart[(size_t)z * (1024 * 1024) + (size_t)row * OUTC + c];
        v[i] = acc;
        s += acc;
        s2 += acc * acc;
    }
    #pragma unroll
    for (int o = 32; o; o >>= 1) {
        s += __shfl_down(s, o);
        s2 += __shfl_down(s2, o);
    }
    const int wid = t >> 6;
    if ((t & 63) == 0) { red[wid] = s; red[4 + wid] = s2; }
    __syncthreads();
    if (t == 0) {
        float ts = red[0] + red[1] + red[2] + red[3];
        float ts2 = red[4] + red[5] + red[6] + red[7];
        float mu = ts * (1.f / OUTC);
        float var = ts2 * (1.f / OUTC) - mu * mu;
        red[0] = mu;
        red[1] = rsqrtf(var + 1e-5f);
    }
    __syncthreads();
    const float mu = red[0], rs = red[1];
    #pragma unroll
    for (int i = 0; i < 4; ++i) {
        const int c = t + 256 * i;
        out[(size_t)row * OUTC + c] = (v[i] - mu) * rs * lw[c] + lb[c];
    }
}

// ---------------------------------------------------------------------------
extern "C" void kernel_launch(void* const* d_in, const int* in_sizes, int n_in,
                              void* d_out, int out_size, void* d_ws, size_t ws_size,
                              hipStream_t stream) {
    const float* x1        = (const float*)d_in[0];   // (1024,1024)
    const float* in_proj_w = (const float*)d_in[1];   // (4096,1024)
    const float* conv_w    = (const float*)d_in[2];   // (2048,1,4)
    const float* conv_b    = (const float*)d_in[3];   // (2048,)
    const float* x_proj_w  = (const float*)d_in[4];   // (96,2048)
    const float* dt_proj_w = (const float*)d_in[5];   // (2048,64)
    const float* dt_proj_b = (const float*)d_in[6];   // (2048,)
    const float* A_log     = (const float*)d_in[7];   // (2048,16)
    const float* Dp        = (const float*)d_in[8];   // (2048,)
    const float* out_proj_w= (const float*)d_in[9];   // (1024,2048)
    const float* ln_w      = (const float*)d_in[10];  // (1024,)
    const float* ln_b      = (const float*)d_in[11];  // (1024,)
    float* out = (float*)d_out;

    // workspace carve-up
    char* p = (char*)d_ws;
    __hip_bfloat16* xa    = (__hip_bfloat16*)p; p += (size_t)1024 * 1024 * 2;  // 2 MB
    __hip_bfloat16* wb1   = (__hip_bfloat16*)p; p += (size_t)4096 * 1024 * 2;  // 8 MB
    __hip_bfloat16* wpb   = (__hip_bfloat16*)p; p += (size_t)128 * 2048 * 2;   // 0.5 MB
    __hip_bfloat16* wob   = (__hip_bfloat16*)p; p += (size_t)1024 * 2048 * 2;  // 4 MB
    __hip_bfloat16* wdb   = (__hip_bfloat16*)p; p += (size_t)2048 * 64 * 2;    // 0.25 MB
    __hip_bfloat16* xsb   = (__hip_bfloat16*)p; p += (size_t)1024 * 2048 * 2;  // 4 MB
    __hip_bfloat16* ybb   = (__hip_bfloat16*)p; p += (size_t)1024 * 2048 * 2;  // 4 MB
    __hip_bfloat16* xdblb = (__hip_bfloat16*)p; p += (size_t)1024 * 128 * 2;   // 0.25 MB
    float* xz    = (float*)p; p += (size_t)1024 * 4096 * 4;                    // 16 MB
    float* xs    = (float*)p; p += (size_t)1024 * 2048 * 4;                    // 8 MB
    float* xdbl  = (float*)p; p += (size_t)1024 * 128 * 4;                     // 0.5 MB
    float* xpart = (float*)p; p += (size_t)XPZ * 1024 * 128 * 4;               // 8 MB
    float* delta = (float*)p; p += (size_t)1024 * 2048 * 4;                    // 8 MB
    float* carryL = (float*)p; p += (size_t)BATCH * NCHUNK * DINNER * DSTATE * 4; // 2 MB
    float* carryP = (float*)p; p += (size_t)BATCH * NCHUNK * DINNER * DSTATE * 4; // 2 MB
    // out_proj partials (16 MB) alias xz: scan B (last reader of xz) precedes
    // out_proj in stream order.
    float* opart = xz;

    // 0. fused bf16 casts (float4-vectorized)
    cast_all_kernel<<<(R4 / 4 + 255) / 256, 256, 0, stream>>>(x1, in_proj_w, out_proj_w,
                                                              x_proj_w, dt_proj_w,
                                                              xa, wb1, wob, wpb, wdb);
    // 1. in_proj: xz = xa @ wb1^T  (1024 x 4096, K=1024) — 1024 blocks (4/CU)
    gemm_t64<<<dim3(64, 16, 1), 256, 0, stream>>>(xa, wb1, xz,
                                                  NROWS, 2 * DINNER, DMODEL, DMODEL, DMODEL);
    // 2. depthwise causal conv + SiLU -> xs (fp32) + xsb (bf16)
    conv_silu_kernel<<<(NROWS * DINNER) / 256, 256, 0, stream>>>(xz, conv_w, conv_b, xs, xsb);
    // 3. x_proj: xpart[z] = xsb @ wpb^T (1024 x 128, K=2048 split 16) — 512 blocks
    gemm_t64<<<dim3(2, 16, XPZ), 256, 0, stream>>>(xsb, wpb, xpart,
                                                   NROWS, 128, DINNER, DINNER, DINNER);
    // 4. reduce partials -> xdbl fp32 + xdblb bf16
    xdbl_reduce_kernel<<<(1024 * 128) / 256, 256, 0, stream>>>(xpart, xdbl, xdblb);
    // 5. dt_proj + softplus -> delta (MFMA, K=64)
    gemm_dtsp<<<dim3(16, 8), 256, 0, stream>>>(xdblb, wdb, dt_proj_b, delta);
    // 6a. scan phase A: per-chunk carries (chunks 0..2 only; 1536 blocks)
    scan_carry_kernel<<<dim3(DINNER / 16, BATCH, NCHUNK - 1), 256, 0, stream>>>(
        delta, xs, xdbl, A_log, carryL, carryP);
    // 6b. scan phase B: combine + apply + gate -> ybb (bf16) (2048 blocks)
    scan_apply_kernel<<<dim3(DINNER / 16, BATCH, NCHUNK), 256, 0, stream>>>(
        delta, xs, xdbl, xz, A_log, Dp, carryL, carryP, ybb);
    // 7. out_proj: opart[z] = ybb @ wob^T (1024 x 1024, K=2048 split 4) — 1024 blocks
    gemm_t64<<<dim3(16, 16, 4), 256, 0, stream>>>(ybb, wob, opart,
                                                  NROWS, OUTC, DINNER, DINNER, DINNER);
    // 8. LayerNorm (+ split-K reduce) -> out
    ln_kernel<<<NROWS, 256, 0, stream>>>(opart, ln_w, ln_b, out);
}

// Round 8
// 198.834 us; speedup vs baseline: 1.0713x; 1.0713x over previous
//
#include <hip/hip_runtime.h>
#include <hip/hip_bf16.h>
#include <math.h>

// Problem constants (from reference)
#define BATCH 4
#define SEQL 256          // L = C = 256
#define DMODEL 1024
#define DINNER 2048
#define DSTATE 16
#define OUTC 1024
#define NROWS (BATCH * SEQL)   // 1024
#define NCHUNK 4
#define CH 64             // SEQL / NCHUNK
#define XPZ 16            // x_proj split-K slices

typedef __attribute__((ext_vector_type(8))) short bf16x8;  // 8 bf16 = 4 VGPRs
typedef __attribute__((ext_vector_type(4))) float f32x4;   // MFMA C/D

// ---------------------------------------------------------------------------
// bf16 MFMA GEMM, C = A @ B^T, 128x64 tile (M x N), split-K over blockIdx.z.
// r6-verified optimum (2 blocks/CU beats both 1/CU 128x128 and 4/CU 64x64).
// 4-deep LDS pipeline (48 KB), counted vmcnt (3 loads/stage/wave: 6/3/0),
// raw s_barrier. Wave layout: 2x2 waves, each owns 64x32 (acc[4][2]).
// DTSP template: fused bias + softplus epilogue (dt_proj), same MFMA chain.
// ---------------------------------------------------------------------------
template <bool DTSP>
__global__ __launch_bounds__(256) void gemm_n64(const __hip_bfloat16* __restrict__ A,
                                                const __hip_bfloat16* __restrict__ B,
                                                float* __restrict__ C,
                                                int M, int N, int K,
                                                int lda, int ldb,
                                                const float* __restrict__ bd) {
    __shared__ __hip_bfloat16 As[4][128 * 32];   // 32 KB
    __shared__ __hip_bfloat16 Bs[4][64 * 32];    // 16 KB
    const int t  = threadIdx.x;
    const int w  = t >> 6;          // wave 0..3
    const int ln = t & 63;
    const int wm = w >> 1, wn = w & 1;
    const int q  = ln >> 4, lr = ln & 15;
    const int m0 = blockIdx.y * 128;
    const int n0 = blockIdx.x * 64;
    const int Kpart = K / gridDim.z;
    const int kbase = blockIdx.z * Kpart;

    f32x4 acc[4][2] = {};

    const __hip_bfloat16* Ag = A + (size_t)m0 * lda + kbase;
    const __hip_bfloat16* Bg = B + (size_t)n0 * ldb + kbase;

    auto stage = [&](int k0, int buf) {
        #pragma unroll
        for (int i = 0; i < 2; ++i) {            // A: 8 KB (2 loads/wave)
            const int c = (i * 4 + w) * 64 + ln;
            const int r = c >> 2, col = (c & 3) * 8;
            __builtin_amdgcn_global_load_lds(
                (const __attribute__((address_space(1))) void*)(Ag + (size_t)r * lda + k0 + col),
                (__attribute__((address_space(3))) void*)(As[buf] + (i * 4 + w) * 512),
                16, 0, 0);
        }
        {                                        // B: 4 KB (1 load/wave)
            const int c = w * 64 + ln;
            const int r = c >> 2, col = (c & 3) * 8;
            __builtin_amdgcn_global_load_lds(
                (const __attribute__((address_space(1))) void*)(Bg + (size_t)r * ldb + k0 + col),
                (__attribute__((address_space(3))) void*)(Bs[buf] + w * 512),
                16, 0, 0);
        }
    };

    const int nk = Kpart / 32;
    for (int s = 0; s < 3 && s < nk; ++s) stage(s * 32, s);

    for (int kk = 0; kk < nk; ++kk) {
        const int last = (kk + 2 < nk - 1) ? (kk + 2) : (nk - 1);
        const int nf = last - kk;      // younger stages in flight (3 loads each)
        if (nf >= 2)      asm volatile("s_waitcnt vmcnt(6)" ::: "memory");
        else if (nf == 1) asm volatile("s_waitcnt vmcnt(3)" ::: "memory");
        else              asm volatile("s_waitcnt vmcnt(0)" ::: "memory");
        __builtin_amdgcn_s_barrier();
        if (kk + 3 < nk) stage((kk + 3) * 32, (kk + 3) & 3);

        const int buf = kk & 3;
        bf16x8 af[4], bfr[2];
        #pragma unroll
        for (int i = 0; i < 4; ++i)
            af[i] = *(const bf16x8*)(As[buf] + (wm * 64 + i * 16 + lr) * 32 + q * 8);
        #pragma unroll
        for (int j = 0; j < 2; ++j)
            bfr[j] = *(const bf16x8*)(Bs[buf] + (wn * 32 + j * 16 + lr) * 32 + q * 8);
        #pragma unroll
        for (int i = 0; i < 4; ++i)
            #pragma unroll
            for (int j = 0; j < 2; ++j)
                acc[i][j] = __builtin_amdgcn_mfma_f32_16x16x32_bf16(af[i], bfr[j], acc[i][j], 0, 0, 0);
    }
    float* Cz = C + (size_t)blockIdx.z * M * N;
    #pragma unroll
    for (int i = 0; i < 4; ++i) {
        const int mrow = m0 + wm * 64 + i * 16 + q * 4;
        #pragma unroll
        for (int j = 0; j < 2; ++j) {
            const int ncol = n0 + wn * 32 + j * 16 + lr;
            if (DTSP) {
                const float bias = bd[ncol];
                #pragma unroll
                for (int r = 0; r < 4; ++r) {
                    float v = acc[i][j][r] + bias;
                    float sp = (v > 20.f) ? v : log1pf(__expf(v));
                    Cz[(size_t)(mrow + r) * N + ncol] = sp;
                }
            } else {
                #pragma unroll
                for (int r = 0; r < 4; ++r)
                    Cz[(size_t)(mrow + r) * N + ncol] = acc[i][j][r];
            }
        }
    }
}

// ---------------------------------------------------------------------------
// Reduce XPZ split-K partials of x_proj -> xdbl fp32 (1024x128) + xdblb bf16.
// ---------------------------------------------------------------------------
__global__ void xdbl_reduce_kernel(const float* __restrict__ part,
                                   float* __restrict__ xdbl,
                                   __hip_bfloat16* __restrict__ xdblb) {
    const int i = blockIdx.x * 256 + threadIdx.x;   // 1024*128
    float s = 0.f;
    #pragma unroll
    for (int z = 0; z < XPZ; ++z) s += part[(size_t)z * (1024 * 128) + i];
    xdbl[i] = s;
    xdblb[i] = __float2bfloat16(s);
}

// ---------------------------------------------------------------------------
// Fused fp32 -> bf16 casts, float4-vectorized (all regions are %4 sized).
// ---------------------------------------------------------------------------
#define R0 (1024 * 1024)
#define R1 (R0 + 4096 * 1024)
#define R2 (R1 + 2048 * 1024)
#define R3 (R2 + 128 * 2048)
#define R4 (R3 + 2048 * 64)

__device__ __forceinline__ ushort4 cvt4(float4 v) {
    __hip_bfloat16 h0 = __float2bfloat16(v.x);
    __hip_bfloat16 h1 = __float2bfloat16(v.y);
    __hip_bfloat16 h2 = __float2bfloat16(v.z);
    __hip_bfloat16 h3 = __float2bfloat16(v.w);
    ushort4 o;
    o.x = *reinterpret_cast<unsigned short*>(&h0);
    o.y = *reinterpret_cast<unsigned short*>(&h1);
    o.z = *reinterpret_cast<unsigned short*>(&h2);
    o.w = *reinterpret_cast<unsigned short*>(&h3);
    return o;
}

__global__ void cast_all_kernel(const float* __restrict__ x1,
                                const float* __restrict__ w_in,
                                const float* __restrict__ w_out,
                                const float* __restrict__ w_xp,
                                const float* __restrict__ w_dt,
                                __hip_bfloat16* __restrict__ xa,
                                __hip_bfloat16* __restrict__ wb1,
                                __hip_bfloat16* __restrict__ wob,
                                __hip_bfloat16* __restrict__ wpb,
                                __hip_bfloat16* __restrict__ wdb) {
    const int i = (blockIdx.x * 256 + threadIdx.x) * 4;
    if (i >= R4) return;
    if (i < R0) {
        *reinterpret_cast<ushort4*>(xa + i) = cvt4(*(const float4*)(x1 + i));
    } else if (i < R1) {
        int j = i - R0;
        *reinterpret_cast<ushort4*>(wb1 + j) = cvt4(*(const float4*)(w_in + j));
    } else if (i < R2) {
        int j = i - R1;
        *reinterpret_cast<ushort4*>(wob + j) = cvt4(*(const float4*)(w_out + j));
    } else if (i < R3) {
        int j = i - R2; int e = j >> 11;
        float4 v = (e < 96) ? *(const float4*)(w_xp + j) : float4{0.f, 0.f, 0.f, 0.f};
        *reinterpret_cast<ushort4*>(wpb + j) = cvt4(v);
    } else {
        int j = i - R3;
        *reinterpret_cast<ushort4*>(wdb + j) = cvt4(*(const float4*)(w_dt + j));
    }
}

// ---------------------------------------------------------------------------
// Depthwise causal conv1d (k=4, left pad 3) + bias + SiLU. Fully coalesced.
// ---------------------------------------------------------------------------
__global__ void conv_silu_kernel(const float* __restrict__ xz,
                                 const float* __restrict__ conv_w,
                                 const float* __restrict__ conv_b,
                                 float* __restrict__ xs,
                                 __hip_bfloat16* __restrict__ xsb) {
    int idx = blockIdx.x * blockDim.x + threadIdx.x;  // (b*L + l)*DINNER + d
    int d = idx & (DINNER - 1);
    int l = (idx >> 11) & (SEQL - 1);
    int b = idx >> 19;
    const float w0 = conv_w[d * 4 + 0];
    const float w1 = conv_w[d * 4 + 1];
    const float w2 = conv_w[d * 4 + 2];
    const float w3 = conv_w[d * 4 + 3];
    float acc = conv_b[d];
    const size_t base = (size_t)(b * SEQL) * (2 * DINNER) + d;
    if (l >= 3) acc += w0 * xz[base + (size_t)(l - 3) * (2 * DINNER)];
    if (l >= 2) acc += w1 * xz[base + (size_t)(l - 2) * (2 * DINNER)];
    if (l >= 1) acc += w2 * xz[base + (size_t)(l - 1) * (2 * DINNER)];
    acc += w3 * xz[base + (size_t)l * (2 * DINNER)];
    float v = acc / (1.f + __expf(-acc));
    xs[idx] = v;
    xsb[idx] = __float2bfloat16(v);
}

// ---------------------------------------------------------------------------
// 16-lane row sum via DPP row_ror rotations (no DS ops).
// ---------------------------------------------------------------------------
__device__ __forceinline__ float row_reduce16(float x) {
    x += __int_as_float(__builtin_amdgcn_update_dpp(0, __float_as_int(x), 0x128, 0xF, 0xF, true));
    x += __int_as_float(__builtin_amdgcn_update_dpp(0, __float_as_int(x), 0x124, 0xF, 0xF, true));
    x += __int_as_float(__builtin_amdgcn_update_dpp(0, __float_as_int(x), 0x122, 0xF, 0xF, true));
    x += __int_as_float(__builtin_amdgcn_update_dpp(0, __float_as_int(x), 0x121, 0xF, 0xF, true));
    return x;
}

// ---------------------------------------------------------------------------
// Chunk-parallel scan, phase A: per-chunk local recurrence (reads xs).
// Grid (128, B, 3): chunk 3's carry is never consumed -> not computed.
// ---------------------------------------------------------------------------
__global__ __launch_bounds__(256) void scan_carry_kernel(const float* __restrict__ delta,
                                                         const float* __restrict__ xs,
                                                         const float* __restrict__ xdbl,
                                                         const float* __restrict__ A_log,
                                                         float* __restrict__ carryL,
                                                         float* __restrict__ carryP) {
    __shared__ float sDU[CH][16][2];   // [l][dl][{dv, dv*xv}]
    __shared__ float sB[CH][16];       // [l][n]
    const int b = blockIdx.y, c = blockIdx.z, dg = blockIdx.x;
    const int t = threadIdx.x;
    const int dl = t >> 4, n = t & 15;
    const int d = dg * 16 + dl;
    const float a = -__expf(A_log[d * DSTATE + n]);
    const int srow = t >> 4, scol = t & 15;
    const int sd = dg * 16 + scol;
    const int rowbase = b * SEQL + c * CH;
    #pragma unroll
    for (int i = 0; i < 4; ++i) {
        const int row = rowbase + i * 16 + srow;
        const float dv = delta[(size_t)row * DINNER + sd];
        const float xv = xs[(size_t)row * DINNER + sd];
        sDU[i * 16 + srow][scol][0] = dv;
        sDU[i * 16 + srow][scol][1] = dv * xv;
        sB[i * 16 + srow][scol] = xdbl[row * 128 + 64 + scol];
    }
    __syncthreads();
    float h = 0.f, P = 1.f;
    #pragma unroll 16
    for (int l = 0; l < CH; ++l) {
        const float e = __expf(sDU[l][dl][0] * a);
        h = e * h + sDU[l][dl][1] * sB[l][n];
        P *= e;
    }
    const size_t ci = (((size_t)(b * NCHUNK + c)) * DINNER + d) * DSTATE + n;
    carryL[ci] = h;
    carryP[ci] = P;
}

// ---------------------------------------------------------------------------
// Chunk-parallel scan, phase B: combine carries (h = P_j h + L_j, j < c) then
// run the 64-step scan with y output (+D*xs, *silu(res), bf16).
// ---------------------------------------------------------------------------
__global__ __launch_bounds__(256) void scan_apply_kernel(const float* __restrict__ delta,
                                                         const float* __restrict__ xs,
                                                         const float* __restrict__ xdbl,
                                                         const float* __restrict__ xz,
                                                         const float* __restrict__ A_log,
                                                         const float* __restrict__ Dp,
                                                         const float* __restrict__ carryL,
                                                         const float* __restrict__ carryP,
                                                         __hip_bfloat16* __restrict__ ybb) {
    __shared__ float sDU[CH][16][2];   // [l][dl][{dv, dv*xv}]
    __shared__ float sBC[CH][16][2];   // [l][n][{B, C}]
    __shared__ float sGW[CH][16][2];   // [l][dl][{g, D*xv*g}]
    const int b = blockIdx.y, c = blockIdx.z, dg = blockIdx.x;
    const int t = threadIdx.x;
    const int dl = t >> 4, n = t & 15;
    const int d = dg * 16 + dl;
    const float a = -__expf(A_log[d * DSTATE + n]);
    const int srow = t >> 4, scol = t & 15;
    const int sd = dg * 16 + scol;
    const float Dstage = Dp[sd];
    const int rowbase = b * SEQL + c * CH;
    #pragma unroll
    for (int i = 0; i < 4; ++i) {
        const int row = rowbase + i * 16 + srow;
        const float dv = delta[(size_t)row * DINNER + sd];
        const float xv = xs[(size_t)row * DINNER + sd];
        const float r  = xz[(size_t)row * (2 * DINNER) + DINNER + sd];
        const float g = r / (1.f + __expf(-r));
        const int lr_ = i * 16 + srow;
        sDU[lr_][scol][0] = dv;
        sDU[lr_][scol][1] = dv * xv;
        sGW[lr_][scol][0] = g;
        sGW[lr_][scol][1] = Dstage * xv * g;
        sBC[lr_][scol][0] = xdbl[row * 128 + 64 + scol];
        sBC[lr_][scol][1] = xdbl[row * 128 + 80 + scol];
    }
    __syncthreads();
    float h = 0.f;
    for (int j = 0; j < c; ++j) {
        const size_t ci = (((size_t)(b * NCHUNK + j)) * DINNER + d) * DSTATE + n;
        h = carryP[ci] * h + carryL[ci];
    }
    #pragma unroll 16
    for (int l = 0; l < CH; ++l) {
        const float e = __expf(sDU[l][dl][0] * a);
        h = e * h + sDU[l][dl][1] * sBC[l][n][0];
        float pr = row_reduce16(h * sBC[l][n][1]);
        if (n == 0) {
            const float y = pr * sGW[l][dl][0] + sGW[l][dl][1];
            ybb[(size_t)(rowbase + l) * DINNER + d] = __float2bfloat16(y);
        }
    }
}

// ---------------------------------------------------------------------------
// LayerNorm over last dim (1024), fused 4-way split-K reduce of out_proj
// partials. block per row, 256 threads x 4 elems.
// ---------------------------------------------------------------------------
__global__ __launch_bounds__(256) void ln_kernel(const float* __restrict__ opart,
                                                 const float* __restrict__ lw,
                                                 const float* __restrict__ lb,
                                                 float* __restrict__ out) {
    __shared__ float red[8];
    const int row = blockIdx.x;
    const int t = threadIdx.x;
    float v[4];
    float s = 0.f, s2 = 0.f;
    #pragma unroll
    for (int i = 0; i < 4; ++i) {
        const int c = t + 256 * i;
        float acc = 0.f;
        #pragma unroll
        for (int z = 0; z < 4; ++z)
            acc += opart[(size_t)z * (1024 * 1024) + (size_t)row * OUTC + c];
        v[i] = acc;
        s += acc;
        s2 += acc * acc;
    }
    #pragma unroll
    for (int o = 32; o; o >>= 1) {
        s += __shfl_down(s, o);
        s2 += __shfl_down(s2, o);
    }
    const int wid = t >> 6;
    if ((t & 63) == 0) { red[wid] = s; red[4 + wid] = s2; }
    __syncthreads();
    if (t == 0) {
        float ts = red[0] + red[1] + red[2] + red[3];
        float ts2 = red[4] + red[5] + red[6] + red[7];
        float mu = ts * (1.f / OUTC);
        float var = ts2 * (1.f / OUTC) - mu * mu;
        red[0] = mu;
        red[1] = rsqrtf(var + 1e-5f);
    }
    __syncthreads();
    const float mu = red[0], rs = red[1];
    #pragma unroll
    for (int i = 0; i < 4; ++i) {
        const int c = t + 256 * i;
        out[(size_t)row * OUTC + c] = (v[i] - mu) * rs * lw[c] + lb[c];
    }
}

// ---------------------------------------------------------------------------
extern "C" void kernel_launch(void* const* d_in, const int* in_sizes, int n_in,
                              void* d_out, int out_size, void* d_ws, size_t ws_size,
                              hipStream_t stream) {
    const float* x1        = (const float*)d_in[0];   // (1024,1024)
    const float* in_proj_w = (const float*)d_in[1];   // (4096,1024)
    const float* conv_w    = (const float*)d_in[2];   // (2048,1,4)
    const float* conv_b    = (const float*)d_in[3];   // (2048,)
    const float* x_proj_w  = (const float*)d_in[4];   // (96,2048)
    const float* dt_proj_w = (const float*)d_in[5];   // (2048,64)
    const float* dt_proj_b = (const float*)d_in[6];   // (2048,)
    const float* A_log     = (const float*)d_in[7];   // (2048,16)
    const float* Dp        = (const float*)d_in[8];   // (2048,)
    const float* out_proj_w= (const float*)d_in[9];   // (1024,2048)
    const float* ln_w      = (const float*)d_in[10];  // (1024,)
    const float* ln_b      = (const float*)d_in[11];  // (1024,)
    float* out = (float*)d_out;

    // workspace carve-up
    char* p = (char*)d_ws;
    __hip_bfloat16* xa    = (__hip_bfloat16*)p; p += (size_t)1024 * 1024 * 2;  // 2 MB
    __hip_bfloat16* wb1   = (__hip_bfloat16*)p; p += (size_t)4096 * 1024 * 2;  // 8 MB
    __hip_bfloat16* wpb   = (__hip_bfloat16*)p; p += (size_t)128 * 2048 * 2;   // 0.5 MB
    __hip_bfloat16* wob   = (__hip_bfloat16*)p; p += (size_t)1024 * 2048 * 2;  // 4 MB
    __hip_bfloat16* wdb   = (__hip_bfloat16*)p; p += (size_t)2048 * 64 * 2;    // 0.25 MB
    __hip_bfloat16* xsb   = (__hip_bfloat16*)p; p += (size_t)1024 * 2048 * 2;  // 4 MB
    __hip_bfloat16* ybb   = (__hip_bfloat16*)p; p += (size_t)1024 * 2048 * 2;  // 4 MB
    __hip_bfloat16* xdblb = (__hip_bfloat16*)p; p += (size_t)1024 * 128 * 2;   // 0.25 MB
    float* xz    = (float*)p; p += (size_t)1024 * 4096 * 4;                    // 16 MB
    float* xs    = (float*)p; p += (size_t)1024 * 2048 * 4;                    // 8 MB
    float* xdbl  = (float*)p; p += (size_t)1024 * 128 * 4;                     // 0.5 MB
    float* xpart = (float*)p; p += (size_t)XPZ * 1024 * 128 * 4;               // 8 MB
    float* delta = (float*)p; p += (size_t)1024 * 2048 * 4;                    // 8 MB
    float* carryL = (float*)p; p += (size_t)BATCH * NCHUNK * DINNER * DSTATE * 4; // 2 MB
    float* carryP = (float*)p; p += (size_t)BATCH * NCHUNK * DINNER * DSTATE * 4; // 2 MB
    // out_proj partials (16 MB) alias xz: scan B (last reader of xz) precedes
    // out_proj in stream order.
    float* opart = xz;

    // 0. fused bf16 casts (float4-vectorized)
    cast_all_kernel<<<(R4 / 4 + 255) / 256, 256, 0, stream>>>(x1, in_proj_w, out_proj_w,
                                                              x_proj_w, dt_proj_w,
                                                              xa, wb1, wob, wpb, wdb);
    // 1. in_proj: xz = xa @ wb1^T  (1024 x 4096, K=1024) — 512 blocks (2/CU)
    gemm_n64<false><<<dim3(64, 8, 1), 256, 0, stream>>>(xa, wb1, xz,
                                                        NROWS, 2 * DINNER, DMODEL,
                                                        DMODEL, DMODEL, nullptr);
    // 2. depthwise causal conv + SiLU -> xs (fp32) + xsb (bf16)
    conv_silu_kernel<<<(NROWS * DINNER) / 256, 256, 0, stream>>>(xz, conv_w, conv_b, xs, xsb);
    // 3. x_proj: xpart[z] = xsb @ wpb^T (1024 x 128, K=2048 split 16) — 256 blocks
    gemm_n64<false><<<dim3(2, 8, XPZ), 256, 0, stream>>>(xsb, wpb, xpart,
                                                         NROWS, 128, DINNER,
                                                         DINNER, DINNER, nullptr);
    // 4. reduce partials -> xdbl fp32 + xdblb bf16
    xdbl_reduce_kernel<<<(1024 * 128) / 256, 256, 0, stream>>>(xpart, xdbl, xdblb);
    // 5. dt_proj + softplus -> delta (1024 x 2048, K=64) — 256 blocks (2/CU)
    gemm_n64<true><<<dim3(32, 8, 1), 256, 0, stream>>>(xdblb, wdb, delta,
                                                       NROWS, DINNER, 64,
                                                       128, 64, dt_proj_b);
    // 6a. scan phase A: per-chunk carries (chunks 0..2 only; 1536 blocks)
    scan_carry_kernel<<<dim3(DINNER / 16, BATCH, NCHUNK - 1), 256, 0, stream>>>(
        delta, xs, xdbl, A_log, carryL, carryP);
    // 6b. scan phase B: combine + apply + gate -> ybb (bf16) (2048 blocks)
    scan_apply_kernel<<<dim3(DINNER / 16, BATCH, NCHUNK), 256, 0, stream>>>(
        delta, xs, xdbl, xz, A_log, Dp, carryL, carryP, ybb);
    // 7. out_proj: opart[z] = ybb @ wob^T (1024 x 1024, K=2048 split 4) — 512 blocks
    gemm_n64<false><<<dim3(16, 8, 4), 256, 0, stream>>>(ybb, wob, opart,
                                                        NROWS, OUTC, DINNER,
                                                        DINNER, DINNER, nullptr);
    // 8. LayerNorm (+ split-K reduce) -> out
    ln_kernel<<<NROWS, 256, 0, stream>>>(opart, ln_w, ln_b, out);
}